// Round 11
// baseline (19.331 us; speedup 1.0000x reference)
//
#include <hip/hip_runtime.h>
#include <hip/hip_bf16.h>

// HeteroSoap via MFMA: c[s*4+n][ab] = sum_atoms f_sn * Y_ab = 16x16 GEMM, K=N.
// Round 11: 4 atoms per lane per iteration.
//  - 3x float4 + 1x int4 fully-coalesced loads (was 16 scalar dword loads)
//  - 4 independent harmonic chains per lane = 4-way ILP (attacks the ~4x
//    latency-stall inflation seen in r1..r10)
//  - LDS staging: lane's 4 consecutive atoms -> ONE ds_write_b128 per comp
//    (16 b128 writes per 256 atoms = 4 per 64 atoms, was 16 b32 per 64)
//  - reads: 2x ds_read_b128 per MFMA (unchanged per-atom), 8 MFMA per iter.
// Tile [16 comps][256 atoms] dwords (lo16=f one-hot, hi16=Y), XOR swizzle
// Xc=(c&7)<<2 on 4-dword groups; atom(D)=D^Xc verified identical on write
// and read, same map for A and B -> MFMA k-order cancels (proven r5..r10).
// C/D layout per m89. Tail: 2-kernel reduce+finalize (ticket), r10 verbatim.

typedef short short8 __attribute__((ext_vector_type(8)));
typedef float f32x4 __attribute__((ext_vector_type(4)));
typedef unsigned int uint4v __attribute__((ext_vector_type(4)));

#define NB 256

__global__ void __launch_bounds__(256) soap_accum(
    const float* __restrict__ coo, const int* __restrict__ numbers,
    int N, float* __restrict__ partials, float* __restrict__ c_ws,
    int* __restrict__ counter)
{
    __shared__ unsigned int lT[4][16][256];  // [wave][comp][atom] f|Y<<16, 64 KB

    // Per-launch init of fused-tail state (accum ends before reduce starts).
    if (blockIdx.x == 0) {
        if (threadIdx.x < 256) c_ws[threadIdx.x] = 0.f;
        if (threadIdx.x == 0) *counter = 0;
    }

    const int lane = threadIdx.x & 63;
    const int w = threadIdx.x >> 6;
    const int g = lane >> 4;            // k-group
    const int comp = lane & 15;         // fragment index dim (A row / B col)

    unsigned int* lTw = &lT[w][0][0];

    const unsigned t4 = (unsigned)((comp & 7) << 2);
    const unsigned rb = (unsigned)(comp << 8);

    f32x4 acc = {0.f, 0.f, 0.f, 0.f};

    const int stride = NB * 1024;       // 4 waves x 256 atoms per block per iter
    for (int base = (blockIdx.x * 4 + w) * 256; base < N; base += stride) {
        int ib = base + 4 * lane;       // this lane's 4 consecutive atoms
        bool valid = ib < N;            // N%4==0 -> group all-or-nothing
        int ic = valid ? ib : N - 4;    // clamp to real atoms (finite Y), f=0

        const float4* cp = (const float4*)(coo + 3 * ic);   // 16B-aligned
        float4 cA = cp[0], cB = cp[1], cC = cp[2];
        int4 nm4 = *(const int4*)(numbers + ic);            // 16B-aligned
        int nm[4];
        nm[0] = valid ? nm4.x : -1; nm[1] = valid ? nm4.y : -1;
        nm[2] = valid ? nm4.z : -1; nm[3] = valid ? nm4.w : -1;
        float ax[4] = {cA.x, cA.w, cB.z, cC.y};
        float ay[4] = {cA.y, cB.x, cB.w, cC.z};
        float az[4] = {cA.z, cB.y, cC.x, cC.w};

        unsigned d[4][16];              // packed (f|Y) per atom per comp
#pragma unroll
        for (int j = 0; j < 4; ++j) {   // 4 independent chains -> ILP
            float x = ax[j] * 0.5f, y = ay[j] * 0.5f, z = az[j] * 0.5f;
            float r2 = x * x + y * y + z * z;
            float dq = sqrtf(r2);
            float tc = fmaxf(1.f - dq * (1.f / 3.f), 0.f);
            float r = __expf(-0.5f * r2) * (tc * tc);
            float fvv[4];
            fvv[0] = r; fvv[1] = r * r2; fvv[2] = fvv[1] * r2; fvv[3] = fvv[2] * r2;

            const float Y00 = 0.28209479177387814f;
            float re11 = -0.34549414947133550f * x;
            float im11 = -0.34549414947133550f * y;
            float re10 =  0.48860251190291992f * z;
            float re22 = -1.11803398874989490f * (x * re11 - y * im11);
            float im22 = -1.11803398874989490f * (x * im11 + y * re11);
            float re21 =  2.23606797749978970f * z * re11;
            float im21 =  2.23606797749978970f * z * im11;
            float re20 =  1.93649167310370850f * (z * re10 - 0.16286750396763996f * r2);
            float re33 = -1.08012344973464350f * (x * re22 - y * im22);
            float im33 = -1.08012344973464350f * (x * im22 + y * re22);
            float re32 =  2.64575131106459070f * z * re22;
            float im32 =  2.64575131106459070f * z * im22;
            float re31 =  2.09165006633518890f * (z * re21 - 0.44721359549995793f * r2 * re11);
            float im31 =  2.09165006633518890f * (z * im21 - 0.44721359549995793f * r2 * im11);
            float re30 =  1.97202659436653870f * (z * re20 - 0.51639777949432220f * r2 * re10);

            float yvv[16];
            yvv[0] = Y00;  yvv[1] = im11; yvv[2]  = im22; yvv[3]  = im33;
            yvv[4] = re11; yvv[5] = re10; yvv[6]  = im21; yvv[7]  = im32;
            yvv[8] = re22; yvv[9] = re21; yvv[10] = re20; yvv[11] = im31;
            yvv[12] = re33; yvv[13] = re32; yvv[14] = re31; yvv[15] = re30;

#pragma unroll
            for (int c = 0; c < 16; ++c) {
                float fsel = (nm[j] == (c >> 2)) ? fvv[c & 3] : 0.f;
                asm("v_cvt_pk_bf16_f32 %0, %1, %2"
                    : "=v"(d[j][c]) : "v"(fsel), "v"(yvv[c]));
            }
        }

        // 16 swizzled b128 writes: comp c, atoms 4*lane..4*lane+3.
#pragma unroll
        for (int c = 0; c < 16; ++c) {
            uint4v vv = {d[0][c], d[1][c], d[2][c], d[3][c]};
            *(uint4v*)&lTw[(c << 8) + ((4 * lane) ^ ((c & 7) << 2))] = vv;
        }

        // 8 MFMAs (K=32 atoms each). Wave-private tile; in-order LDS pipe
        // per wave orders the aliasing writes/reads (proven r5..r10).
#pragma unroll
        for (int m = 0; m < 8; ++m) {
            uint4v q0 = *(const uint4v*)&lTw[rb + 32 * m + (( 8u * g)      ^ t4)];
            uint4v q1 = *(const uint4v*)&lTw[rb + 32 * m + (( 8u * g + 4)  ^ t4)];
            short8 A, B;
#pragma unroll
            for (int e = 0; e < 4; ++e) {
                A[e]     = (short)(q0[e] & 0xffffu);
                A[4 + e] = (short)(q1[e] & 0xffffu);
                B[e]     = (short)(q0[e] >> 16);
                B[4 + e] = (short)(q1[e] >> 16);
            }
            acc = __builtin_amdgcn_mfma_f32_16x16x32_bf16(A, B, acc, 0, 0, 0);
        }
    }

    // C/D layout (m89): lane, reg rr -> c[i=(lane>>4)*4+rr][j=lane&15].
    // Reuse this wave's (idle, wave-private) tile as the reduce buffer.
    float* credw = (float*)&lT[w][0][0];
#pragma unroll
    for (int rr = 0; rr < 4; ++rr)
        credw[((lane >> 4) * 4 + rr) * 16 + (lane & 15)] = acc[rr];
    __syncthreads();

    int tt = threadIdx.x;
    partials[blockIdx.x * 256 + tt] =
        ((float*)&lT[0][0][0])[tt] + ((float*)&lT[1][0][0])[tt] +
        ((float*)&lT[2][0][0])[tt] + ((float*)&lT[3][0][0])[tt];
}

// Fused reduce + finalize, 32 blocks. Each block sums its slice of partials
// into c_ws atomically; last block to finish does the Yr/Yi/nnl contraction.
__global__ void __launch_bounds__(256) soap_reduce_final(
    const float* __restrict__ partials, float* __restrict__ c_ws,
    int* __restrict__ counter, float* __restrict__ out)
{
    __shared__ float cs[256];
    __shared__ int lastflag;
    int t = threadIdx.x;

    float v = 0.f;
    for (int r = blockIdx.x; r < NB; r += 32)
        v += partials[r * 256 + t];           // coalesced, 8 iters
    atomicAdd(&c_ws[t], v);                   // 32 adds/address, device scope
    __syncthreads();
    if (t == 0) {
        __threadfence();                      // release our adds
        lastflag = (atomicAdd(counter, 1) == 31);
    }
    __syncthreads();
    if (!lastflag) return;

    __threadfence();                          // acquire other blocks' adds
    cs[t] = __hip_atomic_load(&c_ws[t], __ATOMIC_RELAXED,
                              __HIP_MEMORY_SCOPE_AGENT);  // L1-bypassing load
    __syncthreads();

    // p1[a,b,n,m,l] = sum_{j<=l} w_j c[b,m,l,j] c[a,n,l,j] (w=1 if j==l else 2)
    // p2[a,b,n,m,l] = sum_{i<l}  2  c[b,m,i,l] c[a,n,i,l]
    // out = (p1+p2) * nnl[n,m,l]
    const float fact[7] = {1.f, 1.f, 2.f, 6.f, 24.f, 120.f, 720.f};
#pragma unroll
    for (int k = 0; k < 4; ++k) {
        int o = k * 256 + t;
        int l = o & 3, m = (o >> 2) & 3, n = (o >> 4) & 3,
            b = (o >> 6) & 3, a = (o >> 8) & 3;
        const float* cbm = &cs[(b * 4 + m) * 16];
        const float* can = &cs[(a * 4 + n) * 16];
        float vv = 0.f;
        for (int j = 0; j <= l; ++j) {
            float wgt = (j == l) ? 1.f : 2.f;
            vv += wgt * cbm[l * 4 + j] * can[l * 4 + j];
        }
        for (int i = 0; i < l; ++i)
            vv += 2.f * cbm[i * 4 + l] * can[i * 4 + l];
        float an = 1.0f / ((float)(2 * l + 1) * (float)(1 << (2 * n + l)) * fact[n] * fact[n + l]);
        float am = 1.0f / ((float)(2 * l + 1) * (float)(1 << (2 * m + l)) * fact[m] * fact[m + l]);
        out[o] = vv * sqrtf(an * am);
    }
}

extern "C" void kernel_launch(void* const* d_in, const int* in_sizes, int n_in,
                              void* d_out, int out_size, void* d_ws, size_t ws_size,
                              hipStream_t stream)
{
    const float* coo = (const float*)d_in[0];
    const int* numbers = (const int*)d_in[1];
    int N = in_sizes[1];                 // 1,000,000 atoms

    float* c_ws = (float*)d_ws;          // [256] accumulated c
    int* counter = (int*)((float*)d_ws + 256);  // ticket counter
    float* partials = (float*)d_ws + 512;       // [NB*256] stage-1 partials
    // ws requirement: (512 + 65536) * 4 B ~= 264 KB.

    hipLaunchKernelGGL(soap_accum, dim3(NB), dim3(256), 0, stream,
                       coo, numbers, N, partials, c_ws, counter);
    hipLaunchKernelGGL(soap_reduce_final, dim3(32), dim3(256), 0, stream,
                       partials, c_ws, counter, (float*)d_out);
}

// Round 12
// 18.254 us; speedup vs baseline: 1.0590x; 1.0590x over previous
//
#include <hip/hip_runtime.h>
#include <hip/hip_bf16.h>

// HeteroSoap via MFMA: c[s*4+n][ab] = sum_atoms f_sn * Y_ab = 16x16 GEMM, K=N.
// Round 12 = round-10 (best, 18.2us) + ONE change: fragment unpack via
// v_perm_b32 (16 ops) instead of and/lshr extracts (32+ ops).
// Evidence r2..r11: wall time tracks issued-op count; pipelining (r8),
// occupancy (r7), fusion (r9), 4-atom ILP (r11) all neutral-or-worse.
// Data path (proven r5..r10): wave-private dword tile [comp][atom]
// (lo16=f one-hot, hi16=Y via v_cvt_pk_bf16_f32), XOR swizzle idx^((c&7)<<2)
// identical on write and read, 16 ds_write_b32 + 4 ds_read_b128 per 64-atom
// chunk, same atom<->k map for A and B so MFMA k-order cancels; C/D per m89.
// Tail: fused reduce+finalize via last-block-done ticket (r9/r10 verbatim).

typedef short short8 __attribute__((ext_vector_type(8)));
typedef float f32x4 __attribute__((ext_vector_type(4)));
typedef unsigned int uint4v __attribute__((ext_vector_type(4)));

#define NB 512

__global__ void __launch_bounds__(256) soap_accum(
    const float* __restrict__ coo, const int* __restrict__ numbers,
    int N, float* __restrict__ partials, float* __restrict__ c_ws,
    int* __restrict__ counter)
{
    __shared__ unsigned int lT[4][16][64];  // [wave][comp][atom] f|Y<<16, 16 KB

    // Per-launch init of fused-tail state (accum ends before reduce starts).
    if (blockIdx.x == 0) {
        if (threadIdx.x < 256) c_ws[threadIdx.x] = 0.f;
        if (threadIdx.x == 0) *counter = 0;
    }

    const int lane = threadIdx.x & 63;
    const int w = threadIdx.x >> 6;
    const int g = lane >> 4;            // k-group
    const int comp = lane & 15;         // fragment index dim (A row / B col)

    unsigned int* lTw = &lT[w][0][0];

    // Loop-invariant read pointers (proven r7/r9/r10): element e of the
    // 4-dword group at base X^t4 holds atom X+e; same map for A and B.
    const unsigned t4 = (unsigned)((comp & 7) << 2);
    const unsigned rb = (unsigned)(comp << 6);
    const uint4v* q0p = (const uint4v*)&lTw[rb + (( 8u * g)          ^ t4)];
    const uint4v* q1p = (const uint4v*)&lTw[rb + (( 8u * g + 4)      ^ t4)];
    const uint4v* q2p = (const uint4v*)&lTw[rb + ((32u + 8u * g)     ^ t4)];
    const uint4v* q3p = (const uint4v*)&lTw[rb + ((32u + 8u * g + 4) ^ t4)];

    f32x4 acc = {0.f, 0.f, 0.f, 0.f};

    const int stride = NB * 256;        // 4 waves x 64 atoms per block per iter
    for (int base = (blockIdx.x * 4 + w) * 64; base < N; base += stride) {
        int i = base + lane;
        int ic = i < N ? i : N - 1;
        float x = coo[3 * ic + 0] * 0.5f;   // xyz = coo / UNIT, UNIT = 2
        float y = coo[3 * ic + 1] * 0.5f;
        float z = coo[3 * ic + 2] * 0.5f;
        int num = numbers[ic];

        float r2 = x * x + y * y + z * z;
        float dq = sqrtf(r2);
        float tc = fmaxf(1.f - dq * (1.f / 3.f), 0.f);
        float r = __expf(-0.5f * r2) * (tc * tc);
        if (i >= N) r = 0.f;                 // tail: zero f-row kills the atom

        float fv[4];
        fv[0] = r; fv[1] = r * r2; fv[2] = fv[1] * r2; fv[3] = fv[2] * r2;

        // Solid harmonics (f32), packed (L+1)x(L+1) row-major:
        const float Y00 = 0.28209479177387814f;
        float re11 = -0.34549414947133550f * x;
        float im11 = -0.34549414947133550f * y;
        float re10 =  0.48860251190291992f * z;
        float re22 = -1.11803398874989490f * (x * re11 - y * im11);
        float im22 = -1.11803398874989490f * (x * im11 + y * re11);
        float re21 =  2.23606797749978970f * z * re11;
        float im21 =  2.23606797749978970f * z * im11;
        float re20 =  1.93649167310370850f * (z * re10 - 0.16286750396763996f * r2);
        float re33 = -1.08012344973464350f * (x * re22 - y * im22);
        float im33 = -1.08012344973464350f * (x * im22 + y * re22);
        float re32 =  2.64575131106459070f * z * re22;
        float im32 =  2.64575131106459070f * z * im22;
        float re31 =  2.09165006633518890f * (z * re21 - 0.44721359549995793f * r2 * re11);
        float im31 =  2.09165006633518890f * (z * im21 - 0.44721359549995793f * r2 * im11);
        float re30 =  1.97202659436653870f * (z * re20 - 0.51639777949432220f * r2 * re10);

        float yv[16];
        yv[0] = Y00;  yv[1] = im11; yv[2]  = im22; yv[3]  = im33;
        yv[4] = re11; yv[5] = re10; yv[6]  = im21; yv[7]  = im32;
        yv[8] = re22; yv[9] = re21; yv[10] = re20; yv[11] = im31;
        yv[12] = re33; yv[13] = re32; yv[14] = re31; yv[15] = re30;

        // Packed swizzled stores: dword = bf16(fsel) | bf16(Y)<<16 in ONE
        // v_cvt_pk_bf16_f32 (S0 -> lo16, S1 -> hi16).
#pragma unroll
        for (int c = 0; c < 16; ++c) {
            float fsel = (num == (c >> 2)) ? fv[c & 3] : 0.f;
            unsigned d;
            asm("v_cvt_pk_bf16_f32 %0, %1, %2" : "=v"(d) : "v"(fsel), "v"(yv[c]));
            lTw[(c << 6) + (lane ^ ((c & 7) << 2))] = d;
        }

        // Wave-private tile: compiler orders the aliasing writes/reads.
        uint4v q0 = *q0p, q1 = *q1p, q2 = *q2p, q3 = *q3p;

        // Fragment build via v_perm_b32: one op per output dword.
        // perm(a, b, sel): result bytes from (a:b), b = bytes 0-3, a = 4-7.
        // LO = lo16(b) | lo16(a)<<16 ; HI = hi16(b) | hi16(a)<<16.
        const unsigned SLO = 0x05040100u, SHI = 0x07060302u;
        union { unsigned u[4]; short8 s; } A0, B0, A1, B1;
        A0.u[0] = __builtin_amdgcn_perm(q0[1], q0[0], SLO);
        A0.u[1] = __builtin_amdgcn_perm(q0[3], q0[2], SLO);
        A0.u[2] = __builtin_amdgcn_perm(q1[1], q1[0], SLO);
        A0.u[3] = __builtin_amdgcn_perm(q1[3], q1[2], SLO);
        B0.u[0] = __builtin_amdgcn_perm(q0[1], q0[0], SHI);
        B0.u[1] = __builtin_amdgcn_perm(q0[3], q0[2], SHI);
        B0.u[2] = __builtin_amdgcn_perm(q1[1], q1[0], SHI);
        B0.u[3] = __builtin_amdgcn_perm(q1[3], q1[2], SHI);
        A1.u[0] = __builtin_amdgcn_perm(q2[1], q2[0], SLO);
        A1.u[1] = __builtin_amdgcn_perm(q2[3], q2[2], SLO);
        A1.u[2] = __builtin_amdgcn_perm(q3[1], q3[0], SLO);
        A1.u[3] = __builtin_amdgcn_perm(q3[3], q3[2], SLO);
        B1.u[0] = __builtin_amdgcn_perm(q2[1], q2[0], SHI);
        B1.u[1] = __builtin_amdgcn_perm(q2[3], q2[2], SHI);
        B1.u[2] = __builtin_amdgcn_perm(q3[1], q3[0], SHI);
        B1.u[3] = __builtin_amdgcn_perm(q3[3], q3[2], SHI);

        acc = __builtin_amdgcn_mfma_f32_16x16x32_bf16(A0.s, B0.s, acc, 0, 0, 0);
        acc = __builtin_amdgcn_mfma_f32_16x16x32_bf16(A1.s, B1.s, acc, 0, 0, 0);
    }

    // C/D layout (m89): lane, reg rr -> c[i=(lane>>4)*4+rr][j=lane&15].
    // Reuse this wave's (idle, wave-private) tile as the reduce buffer.
    float* credw = (float*)&lT[w][0][0];
#pragma unroll
    for (int rr = 0; rr < 4; ++rr)
        credw[((lane >> 4) * 4 + rr) * 16 + (lane & 15)] = acc[rr];
    __syncthreads();

    int tt = threadIdx.x;
    partials[blockIdx.x * 256 + tt] =
        ((float*)&lT[0][0][0])[tt] + ((float*)&lT[1][0][0])[tt] +
        ((float*)&lT[2][0][0])[tt] + ((float*)&lT[3][0][0])[tt];
}

// Fused reduce + finalize, 32 blocks. Each block sums its slice of partials
// into c_ws atomically; last block to finish does the Yr/Yi/nnl contraction.
__global__ void __launch_bounds__(256) soap_reduce_final(
    const float* __restrict__ partials, float* __restrict__ c_ws,
    int* __restrict__ counter, float* __restrict__ out)
{
    __shared__ float cs[256];
    __shared__ int lastflag;
    int t = threadIdx.x;

    float v = 0.f;
    for (int r = blockIdx.x; r < NB; r += 32)
        v += partials[r * 256 + t];           // coalesced, 16 iters
    atomicAdd(&c_ws[t], v);                   // 32 adds/address, device scope
    __syncthreads();
    if (t == 0) {
        __threadfence();                      // release our adds
        lastflag = (atomicAdd(counter, 1) == 31);
    }
    __syncthreads();
    if (!lastflag) return;

    __threadfence();                          // acquire other blocks' adds
    cs[t] = __hip_atomic_load(&c_ws[t], __ATOMIC_RELAXED,
                              __HIP_MEMORY_SCOPE_AGENT);  // L1-bypassing load
    __syncthreads();

    // p1[a,b,n,m,l] = sum_{j<=l} w_j c[b,m,l,j] c[a,n,l,j] (w=1 if j==l else 2)
    // p2[a,b,n,m,l] = sum_{i<l}  2  c[b,m,i,l] c[a,n,i,l]
    // out = (p1+p2) * nnl[n,m,l]
    const float fact[7] = {1.f, 1.f, 2.f, 6.f, 24.f, 120.f, 720.f};
#pragma unroll
    for (int k = 0; k < 4; ++k) {
        int o = k * 256 + t;
        int l = o & 3, m = (o >> 2) & 3, n = (o >> 4) & 3,
            b = (o >> 6) & 3, a = (o >> 8) & 3;
        const float* cbm = &cs[(b * 4 + m) * 16];
        const float* can = &cs[(a * 4 + n) * 16];
        float vv = 0.f;
        for (int j = 0; j <= l; ++j) {
            float wgt = (j == l) ? 1.f : 2.f;
            vv += wgt * cbm[l * 4 + j] * can[l * 4 + j];
        }
        for (int i = 0; i < l; ++i)
            vv += 2.f * cbm[i * 4 + l] * can[i * 4 + l];
        float an = 1.0f / ((float)(2 * l + 1) * (float)(1 << (2 * n + l)) * fact[n] * fact[n + l]);
        float am = 1.0f / ((float)(2 * l + 1) * (float)(1 << (2 * m + l)) * fact[m] * fact[m + l]);
        out[o] = vv * sqrtf(an * am);
    }
}

extern "C" void kernel_launch(void* const* d_in, const int* in_sizes, int n_in,
                              void* d_out, int out_size, void* d_ws, size_t ws_size,
                              hipStream_t stream)
{
    const float* coo = (const float*)d_in[0];
    const int* numbers = (const int*)d_in[1];
    int N = in_sizes[1];                 // 1,000,000 atoms

    float* c_ws = (float*)d_ws;          // [256] accumulated c
    int* counter = (int*)((float*)d_ws + 256);  // ticket counter
    float* partials = (float*)d_ws + 512;       // [NB*256] stage-1 partials
    // ws requirement: (512 + 131072) * 4 B ~= 0.53 MB.

    hipLaunchKernelGGL(soap_accum, dim3(NB), dim3(256), 0, stream,
                       coo, numbers, N, partials, c_ws, counter);
    hipLaunchKernelGGL(soap_reduce_final, dim3(32), dim3(256), 0, stream,
                       partials, c_ws, counter, (float*)d_out);
}

// Round 13
// 17.688 us; speedup vs baseline: 1.0929x; 1.0320x over previous
//
#include <hip/hip_runtime.h>
#include <hip/hip_bf16.h>
#include <hip/hip_fp16.h>

// HeteroSoap via MFMA: c[s*4+n][ab] = sum_atoms f_sn * Y_ab = 16x16 GEMM, K=N.
// Round 13 = round-10 structure with a packed-f16 datapath (2 atoms/lane):
//  - radial part per atom in f32 (exp precision), harmonic chain computed
//    ONCE in _Float16x2 packed ops (atom0 lo, atom1 hi): ~30 -> ~15 VALU/atom
//  - staged dword = f16 pair -> fragment = ONE ds_read_b128, ZERO unpack
//    (r10-r12 spent 16 perm/extract ops per chunk)
//  - v_mfma_f32_16x16x32_f16 (native f16 MFMA, same shape/C-layout as bf16)
//  - f16 mantissa (10b) > bf16 (7b): absmax should drop.
// Pair layout: dword p of row c = comp c of atoms (p, p+64); A and B use the
// SAME map -> MFMA internal k-order cancels (argument proven r5..r12).
// XOR swizzle idx^((c&7)<<2) identical on write & read; (16m+4g)^swz keeps
// 4-dword runs (swz has only bits 2..4; low 2 bits of base are 0).
// NB=512 (proven optimum r10/r11). Tail: fused reduce+finalize ticket (r10).

typedef float f32x4 __attribute__((ext_vector_type(4)));
typedef unsigned int uint4v __attribute__((ext_vector_type(4)));
typedef _Float16 h2 __attribute__((ext_vector_type(2)));
typedef _Float16 half8 __attribute__((ext_vector_type(8)));

#define NB 512

__global__ void __launch_bounds__(256) soap_accum(
    const float* __restrict__ coo, const int* __restrict__ numbers,
    int N, float* __restrict__ partials, float* __restrict__ c_ws,
    int* __restrict__ counter)
{
    __shared__ unsigned int lT[4][2][16][64];  // [wave][A|B][comp][pair] 32 KB

    // Per-launch init of fused-tail state (accum ends before reduce starts).
    if (blockIdx.x == 0) {
        if (threadIdx.x < 256) c_ws[threadIdx.x] = 0.f;
        if (threadIdx.x == 0) *counter = 0;
    }

    const int lane = threadIdx.x & 63;
    const int w = threadIdx.x >> 6;
    const int g = lane >> 4;            // k-group
    const int comp = lane & 15;         // fragment index dim (A row / B col)

    unsigned int* lA = &lT[w][0][0][0];
    unsigned int* lB = &lT[w][1][0][0];

    // Loop-invariant read offsets: MFMA m covers pairs 16m..16m+15; lane
    // (comp,g) reads 4 consecutive swizzled dwords = pairs 16m+4g..+3 =
    // atoms {16m+4g+j, 16m+4g+j+64}. Same map for A and B.
    const unsigned swz = (unsigned)((comp & 7) << 2);
    const unsigned rbase = (unsigned)(comp << 6);
    unsigned rd[4];
#pragma unroll
    for (int m = 0; m < 4; ++m)
        rd[m] = rbase + ((unsigned)(16 * m + 4 * g) ^ swz);

    f32x4 acc = {0.f, 0.f, 0.f, 0.f};

    const int stride = NB * 512;        // 4 waves x 128 atoms per block per iter
    for (int base = (blockIdx.x * 4 + w) * 128; base < N; base += stride) {
        int i0 = base + lane, i1 = base + 64 + lane;
        int ic0 = i0 < N ? i0 : N - 1, ic1 = i1 < N ? i1 : N - 1;
        float X0 = coo[3 * ic0], Y0_ = coo[3 * ic0 + 1], Z0 = coo[3 * ic0 + 2];
        float X1 = coo[3 * ic1], Y1_ = coo[3 * ic1 + 1], Z1 = coo[3 * ic1 + 2];
        int num0 = i0 < N ? numbers[ic0] : -1;
        int num1 = i1 < N ? numbers[ic1] : -1;

        // Radial in f32 per atom (exp-arg precision), store f16.
        float x0 = X0 * 0.5f, y0 = Y0_ * 0.5f, z0 = Z0 * 0.5f;
        float x1 = X1 * 0.5f, y1 = Y1_ * 0.5f, z1 = Z1 * 0.5f;
        float r20 = x0 * x0 + y0 * y0 + z0 * z0;
        float r21 = x1 * x1 + y1 * y1 + z1 * z1;
        float t0 = fmaxf(1.f - sqrtf(r20) * (1.f / 3.f), 0.f);
        float t1 = fmaxf(1.f - sqrtf(r21) * (1.f / 3.f), 0.f);
        float f00 = __expf(-0.5f * r20) * t0 * t0;
        float f01 = __expf(-0.5f * r21) * t1 * t1;

        h2 fpk[4];
        fpk[0] = (h2){(_Float16)f00, (_Float16)f01};
        fpk[1] = (h2){(_Float16)(f00 * r20), (_Float16)(f01 * r21)};
        fpk[2] = (h2){(_Float16)(f00 * r20 * r20), (_Float16)(f01 * r21 * r21)};
        fpk[3] = (h2){(_Float16)(f00 * r20 * r20 * r20), (_Float16)(f01 * r21 * r21 * r21)};

        // Species one-hot as f16 pair masks (invalid atom -> num=-1 -> 0).
        h2 msk[4];
#pragma unroll
        for (int s = 0; s < 4; ++s)
            msk[s] = (h2){(_Float16)(num0 == s ? 1.f : 0.f),
                          (_Float16)(num1 == s ? 1.f : 0.f)};

        // Packed f16 inputs for the harmonic chain (atom0 lo, atom1 hi).
        h2 xp = (h2){(_Float16)x0, (_Float16)x1};
        h2 yp = (h2){(_Float16)y0, (_Float16)y1};
        h2 zp = (h2){(_Float16)z0, (_Float16)z1};
        h2 rp = (h2){(_Float16)r20, (_Float16)r21};

        // Solid harmonics, packed pairs (v_pk_mul/fma_f16):
        h2 re11 = (_Float16)-0.34549414947133550f * xp;
        h2 im11 = (_Float16)-0.34549414947133550f * yp;
        h2 re10 = (_Float16) 0.48860251190291992f * zp;
        h2 re22 = (_Float16)-1.11803398874989490f * (xp * re11 - yp * im11);
        h2 im22 = (_Float16)-1.11803398874989490f * (xp * im11 + yp * re11);
        h2 re21 = (_Float16) 2.23606797749978970f * (zp * re11);
        h2 im21 = (_Float16) 2.23606797749978970f * (zp * im11);
        h2 re20 = (_Float16) 1.93649167310370850f * (zp * re10 - (_Float16)0.16286750396763996f * rp);
        h2 re33 = (_Float16)-1.08012344973464350f * (xp * re22 - yp * im22);
        h2 im33 = (_Float16)-1.08012344973464350f * (xp * im22 + yp * re22);
        h2 re32 = (_Float16) 2.64575131106459070f * (zp * re22);
        h2 im32 = (_Float16) 2.64575131106459070f * (zp * im22);
        h2 re31 = (_Float16) 2.09165006633518890f * (zp * re21 - (_Float16)0.44721359549995793f * (rp * re11));
        h2 im31 = (_Float16) 2.09165006633518890f * (zp * im21 - (_Float16)0.44721359549995793f * (rp * im11));
        h2 re30 = (_Float16) 1.97202659436653870f * (zp * re20 - (_Float16)0.51639777949432220f * (rp * re10));

        h2 ypk[16];
        ypk[0] = (h2){(_Float16)0.28209479177387814f, (_Float16)0.28209479177387814f};
        ypk[1] = im11; ypk[2]  = im22; ypk[3]  = im33;
        ypk[4] = re11; ypk[5]  = re10; ypk[6]  = im21; ypk[7]  = im32;
        ypk[8] = re22; ypk[9]  = re21; ypk[10] = re20; ypk[11] = im31;
        ypk[12] = re33; ypk[13] = re32; ypk[14] = re31; ypk[15] = re30;

        // Swizzled stores: lane owns pair-column `lane`; one b32 per tile/comp.
#pragma unroll
        for (int c = 0; c < 16; ++c) {
            h2 fs = fpk[c & 3] * msk[c >> 2];
            union { h2 h; unsigned u; } ua, ub;
            ua.h = fs; ub.h = ypk[c];
            unsigned idx = (unsigned)(c << 6) + ((unsigned)lane ^ ((unsigned)(c & 7) << 2));
            lA[idx] = ua.u;
            lB[idx] = ub.u;
        }

        // 4 MFMAs (32 atoms each); wave-private tile, in-order LDS per wave.
#pragma unroll
        for (int m = 0; m < 4; ++m) {
            union { uint4v q; half8 h; } A, B;
            A.q = *(const uint4v*)&lA[rd[m]];
            B.q = *(const uint4v*)&lB[rd[m]];
            acc = __builtin_amdgcn_mfma_f32_16x16x32_f16(A.h, B.h, acc, 0, 0, 0);
        }
    }

    // C/D layout (m89): lane, reg rr -> c[i=(lane>>4)*4+rr][j=lane&15].
    // Reuse this wave's (idle, wave-private) tile as the reduce buffer.
    float* credw = (float*)&lT[w][0][0][0];
#pragma unroll
    for (int rr = 0; rr < 4; ++rr)
        credw[((lane >> 4) * 4 + rr) * 16 + (lane & 15)] = acc[rr];
    __syncthreads();

    int tt = threadIdx.x;
    partials[blockIdx.x * 256 + tt] =
        ((float*)&lT[0][0][0][0])[tt] + ((float*)&lT[1][0][0][0])[tt] +
        ((float*)&lT[2][0][0][0])[tt] + ((float*)&lT[3][0][0][0])[tt];
}

// Fused reduce + finalize, 32 blocks. Each block sums its slice of partials
// into c_ws atomically; last block to finish does the Yr/Yi/nnl contraction.
__global__ void __launch_bounds__(256) soap_reduce_final(
    const float* __restrict__ partials, float* __restrict__ c_ws,
    int* __restrict__ counter, float* __restrict__ out)
{
    __shared__ float cs[256];
    __shared__ int lastflag;
    int t = threadIdx.x;

    float v = 0.f;
    for (int r = blockIdx.x; r < NB; r += 32)
        v += partials[r * 256 + t];           // coalesced, 16 iters
    atomicAdd(&c_ws[t], v);                   // 32 adds/address, device scope
    __syncthreads();
    if (t == 0) {
        __threadfence();                      // release our adds
        lastflag = (atomicAdd(counter, 1) == 31);
    }
    __syncthreads();
    if (!lastflag) return;

    __threadfence();                          // acquire other blocks' adds
    cs[t] = __hip_atomic_load(&c_ws[t], __ATOMIC_RELAXED,
                              __HIP_MEMORY_SCOPE_AGENT);  // L1-bypassing load
    __syncthreads();

    // p1[a,b,n,m,l] = sum_{j<=l} w_j c[b,m,l,j] c[a,n,l,j] (w=1 if j==l else 2)
    // p2[a,b,n,m,l] = sum_{i<l}  2  c[b,m,i,l] c[a,n,i,l]
    // out = (p1+p2) * nnl[n,m,l]
    const float fact[7] = {1.f, 1.f, 2.f, 6.f, 24.f, 120.f, 720.f};
#pragma unroll
    for (int k = 0; k < 4; ++k) {
        int o = k * 256 + t;
        int l = o & 3, m = (o >> 2) & 3, n = (o >> 4) & 3,
            b = (o >> 6) & 3, a = (o >> 8) & 3;
        const float* cbm = &cs[(b * 4 + m) * 16];
        const float* can = &cs[(a * 4 + n) * 16];
        float vv = 0.f;
        for (int j = 0; j <= l; ++j) {
            float wgt = (j == l) ? 1.f : 2.f;
            vv += wgt * cbm[l * 4 + j] * can[l * 4 + j];
        }
        for (int i = 0; i < l; ++i)
            vv += 2.f * cbm[i * 4 + l] * can[i * 4 + l];
        float an = 1.0f / ((float)(2 * l + 1) * (float)(1 << (2 * n + l)) * fact[n] * fact[n + l]);
        float am = 1.0f / ((float)(2 * l + 1) * (float)(1 << (2 * m + l)) * fact[m] * fact[m + l]);
        out[o] = vv * sqrtf(an * am);
    }
}

extern "C" void kernel_launch(void* const* d_in, const int* in_sizes, int n_in,
                              void* d_out, int out_size, void* d_ws, size_t ws_size,
                              hipStream_t stream)
{
    const float* coo = (const float*)d_in[0];
    const int* numbers = (const int*)d_in[1];
    int N = in_sizes[1];                 // 1,000,000 atoms

    float* c_ws = (float*)d_ws;          // [256] accumulated c
    int* counter = (int*)((float*)d_ws + 256);  // ticket counter
    float* partials = (float*)d_ws + 512;       // [NB*256] stage-1 partials
    // ws requirement: (512 + 131072) * 4 B ~= 0.53 MB.

    hipLaunchKernelGGL(soap_accum, dim3(NB), dim3(256), 0, stream,
                       coo, numbers, N, partials, c_ws, counter);
    hipLaunchKernelGGL(soap_reduce_final, dim3(32), dim3(256), 0, stream,
                       partials, c_ws, counter, (float*)d_out);
}